// Round 6
// baseline (117.228 us; speedup 1.0000x reference)
//
#include <hip/hip_runtime.h>

typedef unsigned short u16;
typedef __bf16 bf16x8 __attribute__((ext_vector_type(8)));
typedef unsigned short u16x8 __attribute__((ext_vector_type(8)));
typedef float f32x4 __attribute__((ext_vector_type(4)));

union Frag { u16x8 u; bf16x8 b; };

__device__ __forceinline__ u16 f2bf(float f) {
  unsigned u = __builtin_bit_cast(unsigned, f);
  u += 0x7fff + ((u >> 16) & 1);
  return (u16)(u >> 16);
}

__device__ __forceinline__ f32x4 mfma16(bf16x8 a, bf16x8 b, f32x4 c) {
  return __builtin_amdgcn_mfma_f32_16x16x32_bf16(a, b, c, 0, 0, 0);
}

// raw v_exp_f32: computes 2^x
__device__ __forceinline__ float exp2_raw(float x) {
  float r;
  asm("v_exp_f32 %0, %1" : "=v"(r) : "v"(x));
  return r;
}

typedef const __attribute__((address_space(1))) void* as1cv;
typedef __attribute__((address_space(3))) void* as3v;

__device__ __forceinline__ void glds16(const u16* g, u16* l) {
  __builtin_amdgcn_global_load_lds((as1cv)g, (as3v)l, 16, 0, 0);
}

#define FENCE asm volatile("" ::: "memory")

// ---------------- cast x (fp32 -> bf16), vectorized ----------------
__global__ __launch_bounds__(256) void castf_bf(const float* __restrict__ src,
                                                u16* __restrict__ dst, int n4) {
  int i = blockIdx.x * blockDim.x + threadIdx.x;
  int stride = gridDim.x * blockDim.x;
  for (; i < n4; i += stride) {
    float4 v = ((const float4*)src)[i];
    ushort4 o;
    o.x = f2bf(v.x); o.y = f2bf(v.y); o.z = f2bf(v.z); o.w = f2bf(v.w);
    ((ushort4*)dst)[i] = o;
  }
}

// ---------- cast + transpose W [K][N] fp32 -> WT [N][K] bf16 ----------
__global__ __launch_bounds__(256) void cast_transpose(const float* __restrict__ src,
                                                      u16* __restrict__ dst, int K, int N) {
  __shared__ float tile[32][33];
  int tn = N >> 5;
  int bk = blockIdx.x / tn, bn = blockIdx.x % tn;
  int k0 = bk << 5, n0 = bn << 5;
  int tx = threadIdx.x, ty = threadIdx.y;
#pragma unroll
  for (int i = 0; i < 4; i++)
    tile[ty + 8 * i][tx] = src[(size_t)(k0 + ty + 8 * i) * N + n0 + tx];
  __syncthreads();
#pragma unroll
  for (int i = 0; i < 4; i++)
    dst[(size_t)(n0 + ty + 8 * i) * K + k0 + tx] = f2bf(tile[tx][ty + 8 * i]);
}

// ================= 256x256 8-phase GEMM (T2+T3+T4+T5), bf16 out ================
// C[M][N] = A[M][K] * BT[N][K]^T. 512 threads = 8 waves (2M x 4N), BK=64.
// LDS: 2 buf x 4 half-regions (0=Ah0,1=Bh0,2=Bh1,3=Ah1) x [128][64] u16 = 128 KB.
// Phase q of tile t: ds_read quadrant (mh=q>>1, nh=q&1) frags; stage half q of
// tile t+1 (linear gload_lds dest; source pre-XOR-swizzled gran^=(row&7));
// s_barrier; 16 MFMA; counted vmcnt (never 0 in steady state); s_barrier.
// Wait ledger (2 loads per stage): need-before-use covered by vmcnt(4) at
// q0/q1/q3 ends; overwrites land >=2 barriers after last read of old data.
__global__ __launch_bounds__(512) void gemm256(const u16* __restrict__ A,
                                               const u16* __restrict__ BT,
                                               u16* __restrict__ C,
                                               int M, int N, int K, int nbc) {
  __shared__ __align__(16) u16 lds[2][4][8192];
  int nwg = gridDim.x;
  int cpx = nwg >> 3;
  int bid = blockIdx.x;
  int swz = (bid & 7) * cpx + (bid >> 3);      // bijective XCD swizzle (nwg%8==0)
  int br = swz / nbc, bc = swz % nbc;

  int tid = threadIdx.x;
  int w = tid >> 6, l = tid & 63;
  int lg = l >> 4, lq = l & 15;
  int wr = w >> 2, wc = w & 3;

  // staging geometry: thread t covers row rr=t>>3 (of a 64-row chunk),
  // physical granule t&7; logical granule gl = (t&7) ^ (rr&7).
  int rr = tid >> 3;
  int gl = (tid & 7) ^ (rr & 7);
  const u16* Abase = A + (size_t)(br * 256) * K + gl * 8;
  const u16* Bbase = BT + (size_t)(bc * 256) * K + gl * 8;

  f32x4 acc[2][2][4][2];
#pragma unroll
  for (int i = 0; i < 2; ++i)
#pragma unroll
    for (int j = 0; j < 2; ++j)
#pragma unroll
      for (int m = 0; m < 4; ++m)
#pragma unroll
        for (int n = 0; n < 2; ++n)
          acc[i][j][m][n] = (f32x4){0.f, 0.f, 0.f, 0.f};

  auto stage = [&](int tile, int buf, int hh) {
    int kt = tile << 6;
    const u16* s0;
    if (hh == 0)      s0 = Abase + (size_t)rr * K + kt;          // A half 0
    else if (hh == 1) s0 = Bbase + (size_t)rr * K + kt;          // B half 0
    else if (hh == 2) s0 = Bbase + (size_t)(128 + rr) * K + kt;  // B half 1
    else              s0 = Abase + (size_t)(128 + rr) * K + kt;  // A half 1
    u16* d = &lds[buf][hh][w * 512];
    glds16(s0, d);
    glds16(s0 + (size_t)64 * K, d + 4096);
  };

  int NT = K >> 6;
  // prologue: all 4 halves of tile 0; allow last 2 in flight
  stage(0, 0, 0); stage(0, 0, 1); stage(0, 0, 2); stage(0, 0, 3);
  asm volatile("s_waitcnt vmcnt(4)" ::: "memory");
  FENCE; __builtin_amdgcn_s_barrier(); __builtin_amdgcn_sched_barrier(0);

  for (int t = 0; t < NT; ++t) {
    int buf = t & 1;
    int hn = (t + 1 < NT);
#pragma unroll
    for (int q = 0; q < 4; ++q) {
      const int mh = q >> 1, nh = q & 1;
      const u16* Ar = &lds[buf][mh ? 3 : 0][0];
      const u16* Br = &lds[buf][1 + nh][0];
      Frag a[4][2], bb[2][2];
#pragma unroll
      for (int m = 0; m < 4; ++m) {
        int ar = wr * 64 + m * 16 + lq;
#pragma unroll
        for (int kk = 0; kk < 2; ++kk)
          a[m][kk].u = *(const u16x8*)(Ar + ar * 64 + (((kk * 4 + lg) ^ (ar & 7)) << 3));
      }
#pragma unroll
      for (int n = 0; n < 2; ++n) {
        int brr = wc * 32 + n * 16 + lq;
#pragma unroll
        for (int kk = 0; kk < 2; ++kk)
          bb[n][kk].u = *(const u16x8*)(Br + brr * 64 + (((kk * 4 + lg) ^ (brr & 7)) << 3));
      }
      if (hn) stage(t + 1, buf ^ 1, q);
      FENCE; __builtin_amdgcn_s_barrier(); __builtin_amdgcn_sched_barrier(0);
      __builtin_amdgcn_s_setprio(1);
#pragma unroll
      for (int m = 0; m < 4; ++m)
#pragma unroll
        for (int n = 0; n < 2; ++n) {
          acc[mh][nh][m][n] = mfma16(a[m][0].b, bb[n][0].b, acc[mh][nh][m][n]);
          acc[mh][nh][m][n] = mfma16(a[m][1].b, bb[n][1].b, acc[mh][nh][m][n]);
        }
      __builtin_amdgcn_s_setprio(0);
      if (q == 0) {
        if (hn) asm volatile("s_waitcnt vmcnt(4)" ::: "memory");
        else    asm volatile("s_waitcnt vmcnt(2)" ::: "memory");
      } else if (q == 1) {
        if (hn) asm volatile("s_waitcnt vmcnt(4)" ::: "memory");
        else    asm volatile("s_waitcnt vmcnt(0)" ::: "memory");
      } else if (q == 3) {
        if (hn) asm volatile("s_waitcnt vmcnt(4)" ::: "memory");
      }
      FENCE; __builtin_amdgcn_s_barrier(); __builtin_amdgcn_sched_barrier(0);
    }
  }

  // epilogue
#pragma unroll
  for (int mh = 0; mh < 2; ++mh)
#pragma unroll
    for (int m = 0; m < 4; ++m) {
      int row0 = br * 256 + mh * 128 + wr * 64 + m * 16 + lg * 4;
#pragma unroll
      for (int nh = 0; nh < 2; ++nh)
#pragma unroll
        for (int n = 0; n < 2; ++n) {
          int col = bc * 256 + nh * 128 + wc * 32 + n * 16 + lq;
#pragma unroll
          for (int r = 0; r < 4; ++r)
            C[(size_t)(row0 + r) * N + col] = f2bf(acc[mh][nh][m][n][r]);
        }
    }
}

// ------- GEMM: C[M][N] = A[M][K] * BT[N][K]^T  (2-phase double-buffered) -------
template <int FP32OUT>
__global__ __launch_bounds__(256) void gemm_bt(const u16* __restrict__ A,
                                               const u16* __restrict__ BT,
                                               void* __restrict__ Cout,
                                               const float* __restrict__ bias,
                                               int N, int K, int nbc) {
  __shared__ u16 Al[2][128 * 32];
  __shared__ u16 Bl[2][128 * 32];
  int bid = blockIdx.x;
  int br = bid / nbc, bc = bid % nbc;
  int tid = threadIdx.x;
  int w = tid >> 6, l = tid & 63;
  int lg = l >> 4, lq = l & 15;
  int wr = w >> 1, wc = w & 1;

  f32x4 acc[4][4];
#pragma unroll
  for (int m = 0; m < 4; m++)
#pragma unroll
    for (int n = 0; n < 4; n++)
      acc[m][n] = (f32x4){0.f, 0.f, 0.f, 0.f};

  const u16* Ab = A + (size_t)(br * 128 + 32 * w + (l >> 2)) * K + (l & 3) * 8;
  const u16* Bb = BT + (size_t)(bc * 128 + 32 * w + (l >> 2)) * K + (l & 3) * 8;

  auto stage = [&](int it, int buf) {
    int kt = it * 32;
    u16* ald = &Al[buf][32 * w * 32];
    u16* bld = &Bl[buf][32 * w * 32];
    glds16(Ab + kt, ald);
    glds16(Ab + (size_t)16 * K + kt, ald + 16 * 32);
    glds16(Bb + kt, bld);
    glds16(Bb + (size_t)16 * K + kt, bld + 16 * 32);
  };

  int nk = K >> 5;
  stage(0, 0);
  __syncthreads();

  for (int it = 0; it < nk; ++it) {
    int buf = it & 1;
    if (it + 1 < nk) stage(it + 1, buf ^ 1);

    Frag af[4], bf[4];
#pragma unroll
    for (int m = 0; m < 4; m++)
      af[m].u = *(const u16x8*)(&Al[buf][(64 * wr + 16 * m + lq) * 32 + lg * 8]);
#pragma unroll
    for (int n = 0; n < 4; n++)
      bf[n].u = *(const u16x8*)(&Bl[buf][(64 * wc + 16 * n + lq) * 32 + lg * 8]);
    __builtin_amdgcn_s_setprio(1);
#pragma unroll
    for (int m = 0; m < 4; m++)
#pragma unroll
      for (int n = 0; n < 4; n++)
        acc[m][n] = mfma16(af[m].b, bf[n].b, acc[m][n]);
    __builtin_amdgcn_s_setprio(0);
    __syncthreads();
  }

  int row0 = br * 128 + 64 * wr + lg * 4;
  int col0 = bc * 128 + 64 * wc + lq;
  if (FP32OUT) {
    float* C = (float*)Cout;
#pragma unroll
    for (int n = 0; n < 4; n++) {
      float bv = bias[col0 + 16 * n];
#pragma unroll
      for (int m = 0; m < 4; m++)
#pragma unroll
        for (int r = 0; r < 4; r++)
          C[(size_t)(row0 + 16 * m + r) * N + col0 + 16 * n] = acc[m][n][r] + bv;
    }
  } else {
    u16* C = (u16*)Cout;
#pragma unroll
    for (int n = 0; n < 4; n++)
#pragma unroll
      for (int m = 0; m < 4; m++)
#pragma unroll
        for (int r = 0; r < 4; r++)
          C[(size_t)(row0 + 16 * m + r) * N + col0 + 16 * n] = f2bf(acc[m][n][r]);
  }
}

// ------------- build V^T (permuted cols): vt[bh][dh][s'] ------------------
__global__ __launch_bounds__(256) void build_vt(const u16* __restrict__ qkv,
                                                u16* __restrict__ vt) {
  __shared__ u16 t[64][65];
  int bid = blockIdx.x;             // bh*32 + s-tile
  int s0 = (bid & 31) * 64;
  int bh = bid >> 5;
  int b = bh >> 4, h = bh & 15;
  int tid = threadIdx.x;
  int r = tid >> 2, c4 = (tid & 3) * 16;
  const u16* srow = qkv + (size_t)(b * 2048 + s0 + r) * 3072 + 2048 + h * 64 + c4;
  u16x8 v0 = *(const u16x8*)(srow);
  u16x8 v1 = *(const u16x8*)(srow + 8);
#pragma unroll
  for (int j = 0; j < 8; j++) { t[r][c4 + j] = v0[j]; t[r][c4 + 8 + j] = v1[j]; }
  __syncthreads();
  int dh = tid >> 2, sc = (tid & 3) * 16;
  u16 outv[16];
#pragma unroll
  for (int i = 0; i < 16; ++i) {
    int e = sc + i;
    int b32 = e >> 5, e32 = e & 31;
    int k = ((e32 >> 2) & 1) * 16 + (e32 >> 3) * 4 + (e32 & 3);
    outv[i] = t[b32 * 32 + k][dh];
  }
  u16* drow = vt + ((size_t)bh * 64 + dh) * 2048 + s0 + sc;
  *(u16x8*)drow = *(u16x8*)&outv[0];
  *(u16x8*)(drow + 8) = *(u16x8*)&outv[8];
}

// ------------------------------ flash attention -------------------------------
__global__ __launch_bounds__(256) void flash_attn(const u16* __restrict__ qkv,
                                                  const u16* __restrict__ vt,
                                                  u16* __restrict__ aout) {
  __shared__ __align__(16) u16 pool[2][8192];   // per buf: K[64][64] | V^T[64][64]
  const float SL2E = 0.18033688011112043f;      // 0.125 * log2(e)
  int bid = blockIdx.x;
  int bh = bid & 31;
  int qb = 31 - (bid >> 5);
  int b = bh >> 4, h = bh & 15;
  int tid = threadIdx.x;
  int w = tid >> 6, l = tid & 63;
  int lg = l >> 4, lq = l & 15;
  int q0w = qb * 64 + w * 16;
  int qidx = q0w + lq;
  int ntiles = qb + 1;

  const size_t rs = 3072;
  int srw = l >> 3;
  int scol = 8 * ((l & 7) ^ srw);
  const u16* kg = qkv + (size_t)(b * 2048) * rs + 1024 + h * 64;
  const u16* vg = vt + (size_t)bh * 64 * 2048;
  int r0 = (w * 2 + 0) * 8 + srw;
  int r1 = (w * 2 + 1) * 8 + srw;
  int swz = (lq & 7) << 3;

  Frag qf0, qf1;
  const u16* qbase = qkv + (size_t)(b * 2048 + q0w + lq) * rs + h * 64 + lg * 8;
  qf0.u = *(const u16x8*)(qbase);
  qf1.u = *(const u16x8*)(qbase + 32);

  float lam = 0.f;
  f32x4 o[4];
#pragma unroll
  for (int d = 0; d < 4; ++d) o[d] = (f32x4){0.f, 0.f, 0.f, 0.f};

  auto stage = [&](int tile, int buf) {
    int kt2 = tile * 64;
    u16* nb = &pool[buf][0];
    glds16(kg + (size_t)(kt2 + r0) * rs + scol, nb + (w * 2 + 0) * 512);
    glds16(kg + (size_t)(kt2 + r1) * rs + scol, nb + (w * 2 + 1) * 512);
    glds16(vg + (size_t)r0 * 2048 + kt2 + scol, nb + 4096 + (w * 2 + 0) * 512);
    glds16(vg + (size_t)r1 * 2048 + kt2 + scol, nb + 4096 + (w * 2 + 1) * 512);
  };

  stage(0, 0);
  __syncthreads();

  for (int t = 0; t < ntiles; ++t) {
    if (t + 1 < ntiles) stage(t + 1, (t + 1) & 1);
    const u16* Kl = &pool[t & 1][0];
    const u16* Vl = &pool[t & 1][4096];
    int kt = t * 64;

    f32x4 s[4];
    __builtin_amdgcn_s_setprio(1);
#pragma unroll
    for (int sub = 0; sub < 4; ++sub) {
      int row = sub * 16 + lq;
      Frag k0, k1;
      k0.u = *(const u16x8*)(Kl + row * 64 + ((lg * 8) ^ swz));
      k1.u = *(const u16x8*)(Kl + row * 64 + ((32 + lg * 8) ^ swz));
      f32x4 z = {0.f, 0.f, 0.f, 0.f};
      s[sub] = mfma16(k0.b, qf0.b, z);
      s[sub] = mfma16(k1.b, qf1.b, s[sub]);
    }
    __builtin_amdgcn_s_setprio(0);

    if (t == qb) {
#pragma unroll
      for (int sub = 0; sub < 4; ++sub)
#pragma unroll
        for (int r = 0; r < 4; ++r) {
          int key = kt + sub * 16 + lg * 4 + r;
          if (key > qidx) s[sub][r] = -1e30f;
        }
    }

    Frag pf[2];
#pragma unroll
    for (int hf = 0; hf < 2; ++hf)
#pragma unroll
      for (int r = 0; r < 4; ++r) {
        float p0 = exp2_raw(s[2 * hf][r] * SL2E);
        float p1 = exp2_raw(s[2 * hf + 1][r] * SL2E);
        lam += p0 + p1;
        pf[hf].b[r] = (__bf16)p0;
        pf[hf].b[4 + r] = (__bf16)p1;
      }

    __builtin_amdgcn_s_setprio(1);
#pragma unroll
    for (int d = 0; d < 4; ++d) {
      int row = d * 16 + lq;
      Frag vf0, vf1;
      vf0.u = *(const u16x8*)(Vl + row * 64 + ((lg * 8) ^ swz));
      vf1.u = *(const u16x8*)(Vl + row * 64 + ((32 + lg * 8) ^ swz));
      o[d] = mfma16(vf0.b, pf[0].b, o[d]);
      o[d] = mfma16(vf1.b, pf[1].b, o[d]);
    }
    __builtin_amdgcn_s_setprio(0);
    __syncthreads();
  }

  lam += __shfl_xor(lam, 16);
  lam += __shfl_xor(lam, 32);
  float inv = 1.0f / lam;

  u16* Ost = &pool[0][0] + w * (16 * 72);
#pragma unroll
  for (int d = 0; d < 4; ++d)
#pragma unroll
    for (int r = 0; r < 4; ++r)
      Ost[lq * 72 + d * 16 + lg * 4 + r] = f2bf(o[d][r] * inv);
  int q = l >> 2, c16 = (l & 3) * 16;
  u16x8 t0, t1;
#pragma unroll
  for (int j = 0; j < 8; j++) { t0[j] = Ost[q * 72 + c16 + j]; t1[j] = Ost[q * 72 + c16 + 8 + j]; }
  u16* orow = aout + (size_t)(b * 2048 + qb * 64 + w * 16 + q) * 1024 + h * 64 + c16;
  *(u16x8*)orow = t0;
  *(u16x8*)(orow + 8) = t1;
}

// ------------------------------- launcher -------------------------------------
extern "C" void kernel_launch(void* const* d_in, const int* in_sizes, int n_in,
                              void* d_out, int out_size, void* d_ws, size_t ws_size,
                              hipStream_t stream) {
  const float* x    = (const float*)d_in[0];
  const float* wqkv = (const float*)d_in[1];
  const float* wout = (const float*)d_in[2];
  const float* bout = (const float*)d_in[3];
  float* out = (float*)d_out;

  char* ws = (char*)d_ws;
  u16* xb    = (u16*)(ws);                    //  8,388,608 B
  u16* wqkvT = (u16*)(ws + 8388608);          //  6,291,456 B
  u16* woutT = (u16*)(ws + 14680064);         //  2,097,152 B
  u16* qkvb  = (u16*)(ws + 16777216);         // 25,165,824 B
  u16* vtb   = (u16*)(ws + 41943040);         //  8,388,608 B
  u16* aoutb = (u16*)(ws + 50331648);         //  8,388,608 B (total 56 MiB)

  castf_bf<<<1024, 256, 0, stream>>>(x, xb, (4096 * 1024) / 4);
  cast_transpose<<<(1024 / 32) * (3072 / 32), dim3(32, 8), 0, stream>>>(wqkv, wqkvT, 1024, 3072);
  cast_transpose<<<(1024 / 32) * (1024 / 32), dim3(32, 8), 0, stream>>>(wout, woutT, 1024, 1024);

  // qkv = x @ w_qkv   (bf16 out) — 256² 8-phase kernel, grid 16x12=192 (%8==0)
  gemm256<<<(4096 / 256) * (3072 / 256), 512, 0, stream>>>(xb, wqkvT, qkvb,
                                                           4096, 3072, 1024, 3072 / 256);
  build_vt<<<1024, 256, 0, stream>>>(qkvb, vtb);
  flash_attn<<<1024, 256, 0, stream>>>(qkvb, vtb, aoutb);

  // out = attn_out @ w_out + b_out  (fp32 out)
  gemm_bt<1><<<(4096 / 128) * (1024 / 128), 256, 0, stream>>>(aoutb, woutT, out, bout,
                                                              1024, 1024, 1024 / 128);
}

// Round 7
// 106.029 us; speedup vs baseline: 1.1056x; 1.1056x over previous
//
#include <hip/hip_runtime.h>

typedef unsigned short u16;
typedef __bf16 bf16x8 __attribute__((ext_vector_type(8)));
typedef unsigned short u16x8 __attribute__((ext_vector_type(8)));
typedef float f32x4 __attribute__((ext_vector_type(4)));

union Frag { u16x8 u; bf16x8 b; };

__device__ __forceinline__ u16 f2bf(float f) {
  unsigned u = __builtin_bit_cast(unsigned, f);
  u += 0x7fff + ((u >> 16) & 1);
  return (u16)(u >> 16);
}

__device__ __forceinline__ f32x4 mfma16(bf16x8 a, bf16x8 b, f32x4 c) {
  return __builtin_amdgcn_mfma_f32_16x16x32_bf16(a, b, c, 0, 0, 0);
}

// raw v_exp_f32: computes 2^x
__device__ __forceinline__ float exp2_raw(float x) {
  float r;
  asm("v_exp_f32 %0, %1" : "=v"(r) : "v"(x));
  return r;
}

typedef const __attribute__((address_space(1))) void* as1cv;
typedef __attribute__((address_space(3))) void* as3v;

__device__ __forceinline__ void glds16(const u16* g, u16* l) {
  __builtin_amdgcn_global_load_lds((as1cv)g, (as3v)l, 16, 0, 0);
}

// ---------------- cast x (fp32 -> bf16), vectorized ----------------
__global__ __launch_bounds__(256) void castf_bf(const float* __restrict__ src,
                                                u16* __restrict__ dst, int n4) {
  int i = blockIdx.x * blockDim.x + threadIdx.x;
  int stride = gridDim.x * blockDim.x;
  for (; i < n4; i += stride) {
    float4 v = ((const float4*)src)[i];
    ushort4 o;
    o.x = f2bf(v.x); o.y = f2bf(v.y); o.z = f2bf(v.z); o.w = f2bf(v.w);
    ((ushort4*)dst)[i] = o;
  }
}

// -- cast + transpose BOTH weights in one launch: W [K][N] fp32 -> WT [N][K] bf16
// blocks [0, 3072): w_qkv (K=1024, N=3072); [3072, 4096): w_out (K=1024, N=1024)
__global__ __launch_bounds__(256) void cast_transpose2(const float* __restrict__ s1,
                                                       u16* __restrict__ d1,
                                                       const float* __restrict__ s2,
                                                       u16* __restrict__ d2) {
  __shared__ float tile[32][33];
  int bid = blockIdx.x;
  const float* src; u16* dst; int N;
  if (bid < 3072) { src = s1; dst = d1; N = 3072; }
  else            { bid -= 3072; src = s2; dst = d2; N = 1024; }
  const int K = 1024;
  int tn = N >> 5;
  int bk = bid / tn, bn = bid % tn;
  int k0 = bk << 5, n0 = bn << 5;
  int tx = threadIdx.x, ty = threadIdx.y;
#pragma unroll
  for (int i = 0; i < 4; i++)
    tile[ty + 8 * i][tx] = src[(size_t)(k0 + ty + 8 * i) * N + n0 + tx];
  __syncthreads();
#pragma unroll
  for (int i = 0; i < 4; i++)
    dst[(size_t)(n0 + ty + 8 * i) * K + k0 + tx] = f2bf(tile[tx][ty + 8 * i]);
}

// ============ QKV GEMM (128x128, BK=32, 2-phase dbuf, XCD swizzle) =============
// C[M][3072] = A[M][1024] * BT[3072][1024]^T.  bc < 16 -> Q/K cols, normal bf16
// store to qkv. bc >= 16 -> V cols: write DIRECTLY to vt[bh][dh][s'] in the
// flash-permuted column layout (e = (k&3) + ((k>>4)&1)*4 + ((k>>2)&3)*8 within
// each 32-key block) and skip the qkv store (nothing reads qkv's V columns).
__global__ __launch_bounds__(256) void gemm_qkv(const u16* __restrict__ A,
                                                const u16* __restrict__ BT,
                                                u16* __restrict__ C,
                                                u16* __restrict__ vt,
                                                int N, int K, int nbc) {
  __shared__ u16 Al[2][128 * 32];
  __shared__ u16 Bl[2][128 * 32];
  int nwg = gridDim.x;
  int bid = blockIdx.x;
  int swz = (bid & 7) * (nwg >> 3) + (bid >> 3);   // bijective, nwg%8==0
  int br = swz / nbc, bc = swz % nbc;
  int tid = threadIdx.x;
  int w = tid >> 6, l = tid & 63;
  int lg = l >> 4, lq = l & 15;
  int wr = w >> 1, wc = w & 1;

  f32x4 acc[4][4];
#pragma unroll
  for (int m = 0; m < 4; m++)
#pragma unroll
    for (int n = 0; n < 4; n++)
      acc[m][n] = (f32x4){0.f, 0.f, 0.f, 0.f};

  const u16* Ab = A + (size_t)(br * 128 + 32 * w + (l >> 2)) * K + (l & 3) * 8;
  const u16* Bb = BT + (size_t)(bc * 128 + 32 * w + (l >> 2)) * K + (l & 3) * 8;

  auto stage = [&](int it, int buf) {
    int kt = it * 32;
    u16* ald = &Al[buf][32 * w * 32];
    u16* bld = &Bl[buf][32 * w * 32];
    glds16(Ab + kt, ald);
    glds16(Ab + (size_t)16 * K + kt, ald + 16 * 32);
    glds16(Bb + kt, bld);
    glds16(Bb + (size_t)16 * K + kt, bld + 16 * 32);
  };

  int nk = K >> 5;
  stage(0, 0);
  __syncthreads();

  for (int it = 0; it < nk; ++it) {
    int buf = it & 1;
    if (it + 1 < nk) stage(it + 1, buf ^ 1);

    Frag af[4], bf[4];
#pragma unroll
    for (int m = 0; m < 4; m++)
      af[m].u = *(const u16x8*)(&Al[buf][(64 * wr + 16 * m + lq) * 32 + lg * 8]);
#pragma unroll
    for (int n = 0; n < 4; n++)
      bf[n].u = *(const u16x8*)(&Bl[buf][(64 * wc + 16 * n + lq) * 32 + lg * 8]);
    __builtin_amdgcn_s_setprio(1);
#pragma unroll
    for (int m = 0; m < 4; m++)
#pragma unroll
      for (int n = 0; n < 4; n++)
        acc[m][n] = mfma16(af[m].b, bf[n].b, acc[m][n]);
    __builtin_amdgcn_s_setprio(0);
    __syncthreads();
  }

  int row0 = br * 128 + 64 * wr + lg * 4;
  int col0 = bc * 128 + 64 * wc + lq;
  if (bc < 16) {
#pragma unroll
    for (int n = 0; n < 4; n++)
#pragma unroll
      for (int m = 0; m < 4; m++)
#pragma unroll
        for (int r = 0; r < 4; r++)
          C[(size_t)(row0 + 16 * m + r) * N + col0 + 16 * n] = f2bf(acc[m][n][r]);
  } else {
    // V third: transposed + permuted write straight into vt
#pragma unroll
    for (int n = 0; n < 4; n++) {
      int vcol = col0 + 16 * n - 2048;
      int h = vcol >> 6, dh = vcol & 63;
#pragma unroll
      for (int m = 0; m < 4; m++) {
        int s_abs = row0 + 16 * m;              // multiple of 4
        int bb = s_abs >> 11;                   // batch
        int s = s_abs & 2047;
        int e = (s >> 5) * 32 + ((s >> 4) & 1) * 4 + ((s >> 2) & 3) * 8;
        ushort4 v;
        v.x = f2bf(acc[m][n][0]); v.y = f2bf(acc[m][n][1]);
        v.z = f2bf(acc[m][n][2]); v.w = f2bf(acc[m][n][3]);
        *(ushort4*)&vt[((size_t)(bb * 16 + h) * 64 + dh) * 2048 + e] = v;
      }
    }
  }
}

// ------- GEMM2: C[M][N] = A[M][K] * BT[N][K]^T + bias  (fp32 out, swizzled) ----
__global__ __launch_bounds__(256) void gemm_bt(const u16* __restrict__ A,
                                               const u16* __restrict__ BT,
                                               float* __restrict__ Cout,
                                               const float* __restrict__ bias,
                                               int N, int K, int nbc) {
  __shared__ u16 Al[2][128 * 32];
  __shared__ u16 Bl[2][128 * 32];
  int nwg = gridDim.x;
  int bid = blockIdx.x;
  int swz = (bid & 7) * (nwg >> 3) + (bid >> 3);
  int br = swz / nbc, bc = swz % nbc;
  int tid = threadIdx.x;
  int w = tid >> 6, l = tid & 63;
  int lg = l >> 4, lq = l & 15;
  int wr = w >> 1, wc = w & 1;

  f32x4 acc[4][4];
#pragma unroll
  for (int m = 0; m < 4; m++)
#pragma unroll
    for (int n = 0; n < 4; n++)
      acc[m][n] = (f32x4){0.f, 0.f, 0.f, 0.f};

  const u16* Ab = A + (size_t)(br * 128 + 32 * w + (l >> 2)) * K + (l & 3) * 8;
  const u16* Bb = BT + (size_t)(bc * 128 + 32 * w + (l >> 2)) * K + (l & 3) * 8;

  auto stage = [&](int it, int buf) {
    int kt = it * 32;
    u16* ald = &Al[buf][32 * w * 32];
    u16* bld = &Bl[buf][32 * w * 32];
    glds16(Ab + kt, ald);
    glds16(Ab + (size_t)16 * K + kt, ald + 16 * 32);
    glds16(Bb + kt, bld);
    glds16(Bb + (size_t)16 * K + kt, bld + 16 * 32);
  };

  int nk = K >> 5;
  stage(0, 0);
  __syncthreads();

  for (int it = 0; it < nk; ++it) {
    int buf = it & 1;
    if (it + 1 < nk) stage(it + 1, buf ^ 1);

    Frag af[4], bf[4];
#pragma unroll
    for (int m = 0; m < 4; m++)
      af[m].u = *(const u16x8*)(&Al[buf][(64 * wr + 16 * m + lq) * 32 + lg * 8]);
#pragma unroll
    for (int n = 0; n < 4; n++)
      bf[n].u = *(const u16x8*)(&Bl[buf][(64 * wc + 16 * n + lq) * 32 + lg * 8]);
    __builtin_amdgcn_s_setprio(1);
#pragma unroll
    for (int m = 0; m < 4; m++)
#pragma unroll
      for (int n = 0; n < 4; n++)
        acc[m][n] = mfma16(af[m].b, bf[n].b, acc[m][n]);
    __builtin_amdgcn_s_setprio(0);
    __syncthreads();
  }

  int row0 = br * 128 + 64 * wr + lg * 4;
  int col0 = bc * 128 + 64 * wc + lq;
#pragma unroll
  for (int n = 0; n < 4; n++) {
    float bv = bias[col0 + 16 * n];
#pragma unroll
    for (int m = 0; m < 4; m++)
#pragma unroll
      for (int r = 0; r < 4; r++)
        Cout[(size_t)(row0 + 16 * m + r) * N + col0 + 16 * n] = acc[m][n][r] + bv;
  }
}

// ------------------------------ flash attention -------------------------------
// 1024 blocks, one 64-row q-tile each, descending work: qb = 31 - (bid>>5);
// bh = bid&31 keeps each XCD on 4 heads (K/V L2-resident). 4 waves/block,
// KVBLK=64, 32 KiB double-buffered LDS, XOR-swizzled rows, glds16 staging.
// Fixed-reference softmax (m=0): no cross-lane ops in the loop.
__global__ __launch_bounds__(256) void flash_attn(const u16* __restrict__ qkv,
                                                  const u16* __restrict__ vt,
                                                  u16* __restrict__ aout) {
  __shared__ __align__(16) u16 pool[2][8192];   // per buf: K[64][64] | V^T[64][64]
  const float SL2E = 0.18033688011112043f;      // 0.125 * log2(e)
  int bid = blockIdx.x;
  int bh = bid & 31;
  int qb = 31 - (bid >> 5);
  int b = bh >> 4, h = bh & 15;
  int tid = threadIdx.x;
  int w = tid >> 6, l = tid & 63;
  int lg = l >> 4, lq = l & 15;
  int q0w = qb * 64 + w * 16;
  int qidx = q0w + lq;
  int ntiles = qb + 1;

  const size_t rs = 3072;
  int srw = l >> 3;
  int scol = 8 * ((l & 7) ^ srw);
  const u16* kg = qkv + (size_t)(b * 2048) * rs + 1024 + h * 64;
  const u16* vg = vt + (size_t)bh * 64 * 2048;
  int r0 = (w * 2 + 0) * 8 + srw;
  int r1 = (w * 2 + 1) * 8 + srw;
  int swz = (lq & 7) << 3;

  Frag qf0, qf1;
  const u16* qbase = qkv + (size_t)(b * 2048 + q0w + lq) * rs + h * 64 + lg * 8;
  qf0.u = *(const u16x8*)(qbase);
  qf1.u = *(const u16x8*)(qbase + 32);

  float lam = 0.f;
  f32x4 o[4];
#pragma unroll
  for (int d = 0; d < 4; ++d) o[d] = (f32x4){0.f, 0.f, 0.f, 0.f};

  auto stage = [&](int tile, int buf) {
    int kt2 = tile * 64;
    u16* nb = &pool[buf][0];
    glds16(kg + (size_t)(kt2 + r0) * rs + scol, nb + (w * 2 + 0) * 512);
    glds16(kg + (size_t)(kt2 + r1) * rs + scol, nb + (w * 2 + 1) * 512);
    glds16(vg + (size_t)r0 * 2048 + kt2 + scol, nb + 4096 + (w * 2 + 0) * 512);
    glds16(vg + (size_t)r1 * 2048 + kt2 + scol, nb + 4096 + (w * 2 + 1) * 512);
  };

  stage(0, 0);
  __syncthreads();

  for (int t = 0; t < ntiles; ++t) {
    if (t + 1 < ntiles) stage(t + 1, (t + 1) & 1);
    const u16* Kl = &pool[t & 1][0];
    const u16* Vl = &pool[t & 1][4096];
    int kt = t * 64;

    f32x4 s[4];
    __builtin_amdgcn_s_setprio(1);
#pragma unroll
    for (int sub = 0; sub < 4; ++sub) {
      int row = sub * 16 + lq;
      Frag k0, k1;
      k0.u = *(const u16x8*)(Kl + row * 64 + ((lg * 8) ^ swz));
      k1.u = *(const u16x8*)(Kl + row * 64 + ((32 + lg * 8) ^ swz));
      f32x4 z = {0.f, 0.f, 0.f, 0.f};
      s[sub] = mfma16(k0.b, qf0.b, z);
      s[sub] = mfma16(k1.b, qf1.b, s[sub]);
    }
    __builtin_amdgcn_s_setprio(0);

    if (t == qb) {
#pragma unroll
      for (int sub = 0; sub < 4; ++sub)
#pragma unroll
        for (int r = 0; r < 4; ++r) {
          int key = kt + sub * 16 + lg * 4 + r;
          if (key > qidx) s[sub][r] = -1e30f;
        }
    }

    Frag pf[2];
#pragma unroll
    for (int hf = 0; hf < 2; ++hf)
#pragma unroll
      for (int r = 0; r < 4; ++r) {
        float p0 = exp2_raw(s[2 * hf][r] * SL2E);
        float p1 = exp2_raw(s[2 * hf + 1][r] * SL2E);
        lam += p0 + p1;
        pf[hf].b[r] = (__bf16)p0;
        pf[hf].b[4 + r] = (__bf16)p1;
      }

    __builtin_amdgcn_s_setprio(1);
#pragma unroll
    for (int d = 0; d < 4; ++d) {
      int row = d * 16 + lq;
      Frag vf0, vf1;
      vf0.u = *(const u16x8*)(Vl + row * 64 + ((lg * 8) ^ swz));
      vf1.u = *(const u16x8*)(Vl + row * 64 + ((32 + lg * 8) ^ swz));
      o[d] = mfma16(vf0.b, pf[0].b, o[d]);
      o[d] = mfma16(vf1.b, pf[1].b, o[d]);
    }
    __builtin_amdgcn_s_setprio(0);
    __syncthreads();
  }

  lam += __shfl_xor(lam, 16);
  lam += __shfl_xor(lam, 32);
  float inv = 1.0f / lam;

  u16* Ost = &pool[0][0] + w * (16 * 72);
#pragma unroll
  for (int d = 0; d < 4; ++d)
#pragma unroll
    for (int r = 0; r < 4; ++r)
      Ost[lq * 72 + d * 16 + lg * 4 + r] = f2bf(o[d][r] * inv);
  int q = l >> 2, c16 = (l & 3) * 16;
  u16x8 t0, t1;
#pragma unroll
  for (int j = 0; j < 8; j++) { t0[j] = Ost[q * 72 + c16 + j]; t1[j] = Ost[q * 72 + c16 + 8 + j]; }
  u16* orow = aout + (size_t)(b * 2048 + qb * 64 + w * 16 + q) * 1024 + h * 64 + c16;
  *(u16x8*)orow = t0;
  *(u16x8*)(orow + 8) = t1;
}

// ------------------------------- launcher -------------------------------------
extern "C" void kernel_launch(void* const* d_in, const int* in_sizes, int n_in,
                              void* d_out, int out_size, void* d_ws, size_t ws_size,
                              hipStream_t stream) {
  const float* x    = (const float*)d_in[0];
  const float* wqkv = (const float*)d_in[1];
  const float* wout = (const float*)d_in[2];
  const float* bout = (const float*)d_in[3];
  float* out = (float*)d_out;

  char* ws = (char*)d_ws;
  u16* xb    = (u16*)(ws);                    //  8,388,608 B
  u16* wqkvT = (u16*)(ws + 8388608);          //  6,291,456 B
  u16* woutT = (u16*)(ws + 14680064);         //  2,097,152 B
  u16* qkvb  = (u16*)(ws + 16777216);         // 25,165,824 B
  u16* vtb   = (u16*)(ws + 41943040);         //  8,388,608 B
  u16* aoutb = (u16*)(ws + 50331648);         //  8,388,608 B (total 56 MiB)

  castf_bf<<<1024, 256, 0, stream>>>(x, xb, (4096 * 1024) / 4);
  cast_transpose2<<<3072 + 1024, dim3(32, 8), 0, stream>>>(wqkv, wqkvT, wout, woutT);

  // qkv = x @ w_qkv; V third lands directly in vt (permuted, transposed)
  gemm_qkv<<<(4096 / 128) * (3072 / 128), 256, 0, stream>>>(xb, wqkvT, qkvb, vtb,
                                                            3072, 1024, 3072 / 128);
  flash_attn<<<1024, 256, 0, stream>>>(qkvb, vtb, aoutb);

  // out = attn_out @ w_out + b_out  (fp32 out)
  gemm_bt<<<(4096 / 128) * (1024 / 128), 256, 0, stream>>>(aoutb, woutT, out, bout,
                                                           1024, 1024, 1024 / 128);
}